// Round 2
// baseline (1721.626 us; speedup 1.0000x reference)
//
#include <hip/hip_runtime.h>

#define NN 25600
#define EE 409600
#define BB 64
#define NGR 400
#define DD 128
#define HH 64
#define RR 32
#define EA 204800              // available (odd) edges
#define TPL (EA/32)            // tiles per label bucket = 6400

// workspace layout (float offsets)
#define OFF_AGGE   0
#define OFF_AGGO   1638400
#define OFF_NMASK  3276800
#define OFF_POOLF  3302400
#define OFF_POOLS  3304448
#define OFF_CNT    3306496
#define OFF_LCOUNT 3306560     // 4 uints
#define OFF_SEGKEY 3306568     // 64 u64
#define ZERO_END   3306752
#define OFF_H      3306752
#define OFF_NRA    4945152
#define OFF_BIAS1  5764352
#define OFF_ELIST  5772544     // 4*EA ints

__device__ __forceinline__ float eluf(float v){ return v > 0.f ? v : expm1f(v); }

__device__ __forceinline__ unsigned long long packkey(float f, unsigned idx){
  unsigned u = __float_as_uint(f);
  u = (u & 0x80000000u) ? ~u : (u | 0x80000000u);
  return ((unsigned long long)u << 32) | (unsigned long long)(0xFFFFFFFFu - idx);
}

// ---------------- h = elu(x @ Wm1) ----------------
__global__ __launch_bounds__(256) void k_h(const float* __restrict__ x,
                                           const float* __restrict__ Wm1,
                                           float* __restrict__ h)
{
  __shared__ float xs[64][129];
  const int tid = threadIdx.x;
  const int n0 = blockIdx.x * 64;
  for (int idx = tid; idx < 64*128; idx += 256){
    int r = idx >> 7, c = idx & 127;
    xs[r][c] = x[(n0 + r)*DD + c];
  }
  __syncthreads();
  const int m = tid & 63, ng = tid >> 6;       // 4 n-groups of 16
  float4 acc[4];
  #pragma unroll
  for (int c = 0; c < 4; ++c) acc[c] = make_float4(0.f,0.f,0.f,0.f);
  for (int k = 0; k < 128; ++k){
    const float a = xs[m][k];
    const float* wr = Wm1 + k*64 + ng*16;
    #pragma unroll
    for (int c = 0; c < 4; ++c){
      const float4 w = *(const float4*)(wr + 4*c);
      acc[c].x += a*w.x; acc[c].y += a*w.y; acc[c].z += a*w.z; acc[c].w += a*w.w;
    }
  }
  float* hp = h + (n0 + m)*HH + ng*16;
  #pragma unroll
  for (int c = 0; c < 4; ++c){
    hp[4*c+0] = eluf(acc[c].x); hp[4*c+1] = eluf(acc[c].y);
    hp[4*c+2] = eluf(acc[c].z); hp[4*c+3] = eluf(acc[c].w);
  }
}

// ---------------- edge aggregation (parity split) + nmask ----------------
__global__ __launch_bounds__(256) void k_edges(const int* __restrict__ ei,
                                               const float* __restrict__ h,
                                               float* __restrict__ aggE,
                                               float* __restrict__ aggO,
                                               float* __restrict__ nmask)
{
  const int gidx = blockIdx.x*256 + threadIdx.x;   // EE*16 threads exactly
  const int e = gidx >> 4, c = gidx & 15;
  const int s = ei[e], d = ei[EE + e];
  const float4 v = *(const float4*)(h + s*HH + c*4);
  float* agg = (e & 1) ? aggO : aggE;
  float* ap = agg + d*HH + c*4;
  atomicAdd(ap+0, v.x); atomicAdd(ap+1, v.y);
  atomicAdd(ap+2, v.z); atomicAdd(ap+3, v.w);
  if (((e & 1) == 0) && (c == 0)){ nmask[s] = 1.0f; nmask[d] = 1.0f; }
}

// ---------------- node reps + pooled sums ----------------
__global__ __launch_bounds__(256) void k_node(const float* __restrict__ h,
                                              const float* __restrict__ aggE,
                                              const float* __restrict__ aggO,
                                              const float* __restrict__ Wm2,
                                              const float* __restrict__ nmask,
                                              float* __restrict__ nra,
                                              float* __restrict__ poolF,
                                              float* __restrict__ poolS,
                                              float* __restrict__ cntArr)
{
  __shared__ float hs[8][64], ae[8][64], ao[8][64];
  __shared__ float wm[64][32];
  const int tid = threadIdx.x;
  const int n0 = blockIdx.x * 8;
  for (int idx = tid; idx < 512; idx += 256){
    int i = idx >> 6, k = idx & 63, n = n0 + i;
    hs[i][k] = h[n*HH + k];
    ae[i][k] = aggE[n*HH + k];
    ao[i][k] = aggO[n*HH + k];
  }
  for (int idx = tid; idx < 2048; idx += 256) wm[idx >> 5][idx & 31] = Wm2[idx];
  __syncthreads();
  const int i = tid >> 5, r = tid & 31;
  const int n = n0 + i;
  float aF = 0.f, aS = 0.f, aA = 0.f;
  #pragma unroll 4
  for (int k = 0; k < 64; ++k){
    const float th = hs[i][k], te = ae[i][k], to = ao[i][k], w = wm[k][r];
    aF += (th + te + to) * w;
    aS += (th + te) * w;
    aA += (th + to) * w;
  }
  aF = eluf(aF); aS = eluf(aS); aA = eluf(aA);
  nra[n*RR + r] = aA;
  const int g = n / NGR;
  atomicAdd(&poolF[g*RR + r], aF);
  const float msk = nmask[n];
  if (msk != 0.f){
    atomicAdd(&poolS[g*RR + r], aS);
    if (r == 0) atomicAdd(&cntArr[g], 1.0f);
  }
}

// ---------------- per-graph diff and explainer bias ----------------
__global__ __launch_bounds__(128) void k_graph(const float* __restrict__ poolF,
                                               const float* __restrict__ poolS,
                                               const float* __restrict__ cnt,
                                               const float* __restrict__ Wg,
                                               const int* __restrict__ y,
                                               const float* __restrict__ We1,
                                               const float* __restrict__ be1,
                                               float* __restrict__ bias1)
{
  __shared__ float pd[32];
  __shared__ float dg[64];
  const int g = blockIdx.x, tid = threadIdx.x;
  if (tid < 32){
    const float c = cnt[g];
    const float pf = poolF[g*RR + tid] * (1.0f/400.0f);
    const float ps = poolS[g*RR + tid] / fmaxf(c, 1.0f);
    pd[tid] = pf - ps;
  }
  __syncthreads();
  if (tid < 64){
    float a = 0.f;
    #pragma unroll
    for (int r = 0; r < 32; ++r) a += pd[r] * Wg[r*64 + tid];
    dg[tid] = a;
  }
  __syncthreads();
  const int l = y[g];
  float acc = be1[l*128 + tid];
  #pragma unroll 8
  for (int j = 0; j < 64; ++j) acc += dg[j] * We1[l*16384 + (64 + j)*128 + tid];
  bias1[g*128 + tid] = acc;
}

// ---------------- bucket available edges by graph label ----------------
__global__ __launch_bounds__(256) void k_bucket(const int* __restrict__ ei,
                                                const int* __restrict__ y,
                                                unsigned* __restrict__ lcount,
                                                int* __restrict__ elist)
{
  const int i = blockIdx.x*256 + threadIdx.x;   // EA threads exactly
  const int e = 2*i + 1;
  const int s = ei[e];
  const int l = y[s / NGR];
  const int lane = threadIdx.x & 63;
  #pragma unroll
  for (int lb = 0; lb < 4; ++lb){
    const unsigned long long msk = __ballot(l == lb);
    if (l == lb){
      const int leader = __builtin_ctzll(msk);
      const unsigned cnt = (unsigned)__popcll(msk);
      unsigned base = 0;
      if (lane == leader) base = atomicAdd(&lcount[lb], cnt);
      base = (unsigned)__shfl((int)base, leader);
      const unsigned rank = (unsigned)__popcll(msk & ((1ull << lane) - 1ull));
      elist[lb*EA + (int)(base + rank)] = i;
    }
  }
}

// ---------------- fused per-edge MLP ----------------
template<int K, int N, bool DOELU, int SIN, int SOUT>
__device__ __forceinline__ void layerfn(const float (*__restrict__ in)[SIN],
                                        float (*__restrict__ out)[SOUT],
                                        const float* __restrict__ W,
                                        const float* __restrict__ bA,
                                        const float* __restrict__ bB,
                                        int m, int ng)
{
  constexpr int NCH = N / 64;   // float4 chunks per thread
  float4 a0[NCH], a1[NCH];
  #pragma unroll
  for (int c = 0; c < NCH; ++c){
    a0[c] = *(const float4*)(bA + ng*4 + 64*c);
    a1[c] = *(const float4*)(bB + ng*4 + 64*c);
  }
  #pragma unroll 4
  for (int k = 0; k < K; ++k){
    const float x0 = in[m][k];
    const float x1 = in[m+16][k];
    const float* wr = W + k*N + ng*4;
    #pragma unroll
    for (int c = 0; c < NCH; ++c){
      const float4 w = *(const float4*)(wr + 64*c);
      a0[c].x += x0*w.x; a0[c].y += x0*w.y; a0[c].z += x0*w.z; a0[c].w += x0*w.w;
      a1[c].x += x1*w.x; a1[c].y += x1*w.y; a1[c].z += x1*w.z; a1[c].w += x1*w.w;
    }
  }
  #pragma unroll
  for (int c = 0; c < NCH; ++c){
    const int n = ng*4 + 64*c;
    float v;
    v = a0[c].x; if (DOELU) v = eluf(v); out[m][n+0] = v;
    v = a0[c].y; if (DOELU) v = eluf(v); out[m][n+1] = v;
    v = a0[c].z; if (DOELU) v = eluf(v); out[m][n+2] = v;
    v = a0[c].w; if (DOELU) v = eluf(v); out[m][n+3] = v;
    v = a1[c].x; if (DOELU) v = eluf(v); out[m+16][n+0] = v;
    v = a1[c].y; if (DOELU) v = eluf(v); out[m+16][n+1] = v;
    v = a1[c].z; if (DOELU) v = eluf(v); out[m+16][n+2] = v;
    v = a1[c].w; if (DOELU) v = eluf(v); out[m+16][n+3] = v;
  }
}

__global__ __launch_bounds__(256) void k_mlp(const float* __restrict__ nra,
                                             const int* __restrict__ ei,
                                             const float* __restrict__ W1, const float* __restrict__ b1,
                                             const float* __restrict__ W2, const float* __restrict__ b2,
                                             const float* __restrict__ W3, const float* __restrict__ b3,
                                             const float* __restrict__ We1,
                                             const float* __restrict__ We2, const float* __restrict__ be2,
                                             const float* __restrict__ We3, const float* __restrict__ be3,
                                             const float* __restrict__ bias1,
                                             const int* __restrict__ elist,
                                             const unsigned* __restrict__ lcount,
                                             float* __restrict__ probs,
                                             unsigned long long* __restrict__ segkey)
{
  __shared__ float X[32][261];
  __shared__ float Y[32][133];
  __shared__ int iA[32], sA[32], dA[32], gA[32];
  const int l = blockIdx.x / TPL;
  const int t = blockIdx.x % TPL;
  const unsigned cnt = lcount[l];
  const int base = t * 32;
  if ((unsigned)base >= cnt) return;
  const int valid = min(32, (int)(cnt - (unsigned)base));
  const int tid = threadIdx.x;
  if (tid < 32){
    const int mm = (tid < valid) ? tid : 0;
    const int i = elist[l*EA + base + mm];
    const int e = 2*i + 1;
    const int s = ei[e], d = ei[EE + e];
    iA[tid] = i; sA[tid] = s; dA[tid] = d; gA[tid] = s / NGR;
  }
  __syncthreads();
  { // gather in0 = [nr_ava[src] | nr_ava[dst]] into Y[m][0..63]
    // 8 threads per row; each loads 8 floats (two float4) => full 64 columns
    const int m = tid >> 3, q = tid & 7;
    const int node = (q < 4) ? sA[m] : dA[m];
    const int off = (q & 3) * 8;
    const float4 v0 = *(const float4*)(nra + node*RR + off);
    const float4 v1 = *(const float4*)(nra + node*RR + off + 4);
    const int c0 = ((q < 4) ? 0 : 32) + off;
    Y[m][c0+0] = v0.x; Y[m][c0+1] = v0.y; Y[m][c0+2] = v0.z; Y[m][c0+3] = v0.w;
    Y[m][c0+4] = v1.x; Y[m][c0+5] = v1.y; Y[m][c0+6] = v1.z; Y[m][c0+7] = v1.w;
  }
  __syncthreads();
  const int m = tid & 15, ng = tid >> 4;
  layerfn< 64,256,true ,133,261>(Y, X, W1, b1, b1, m, ng);
  __syncthreads();
  layerfn<256,128,true ,261,133>(X, Y, W2, b2, b2, m, ng);
  __syncthreads();
  layerfn<128, 64,false,133,261>(Y, X, W3, b3, b3, m, ng);
  __syncthreads();
  layerfn< 64,128,true ,261,133>(X, Y, We1 + l*16384,
                                 bias1 + gA[m]*128, bias1 + gA[m+16]*128, m, ng);
  __syncthreads();
  layerfn<128, 64,true ,133,261>(Y, X, We2 + l*8192, be2 + l*64, be2 + l*64, m, ng);
  __syncthreads();
  if (tid < valid){
    const float* w3p = We3 + l*64;
    float s = 0.f;
    #pragma unroll 8
    for (int k = 0; k < 64; ++k) s += X[tid][k] * w3p[k];
    s += be3[l];
    const int i = iA[tid];
    probs[i] = s;
    atomicMax(&segkey[gA[tid]], packkey(s, (unsigned)i));
  }
}

// ---------------- finalize outputs ----------------
__global__ void k_final(const unsigned long long* __restrict__ segkey, float* __restrict__ out)
{
  const int g = threadIdx.x;
  if (g < BB){
    const unsigned long long key = segkey[g];
    const unsigned u = (unsigned)(key >> 32);
    const float mx = (u & 0x80000000u) ? __uint_as_float(u & 0x7FFFFFFFu)
                                       : __uint_as_float(~u);
    const unsigned idx = 0xFFFFFFFFu - (unsigned)(key & 0xFFFFFFFFull);
    out[EA + g]        = mx;          // seg_max
    out[EA + BB + g]   = (float)idx;  // added_actions
    out[EA + 2*BB + g] = (float)g;    // unique_batch
  }
}

extern "C" void kernel_launch(void* const* d_in, const int* in_sizes, int n_in,
                              void* d_out, int out_size, void* d_ws, size_t ws_size,
                              hipStream_t stream)
{
  (void)in_sizes; (void)n_in; (void)out_size; (void)ws_size;
  const float* x   = (const float*)d_in[0];
  const int*   ei  = (const int*)  d_in[1];
  const int*   y   = (const int*)  d_in[3];
  const float* Wm1 = (const float*)d_in[5];
  const float* Wm2 = (const float*)d_in[6];
  const float* Wg  = (const float*)d_in[7];
  const float* W1  = (const float*)d_in[8];
  const float* b1  = (const float*)d_in[9];
  const float* W2  = (const float*)d_in[10];
  const float* b2  = (const float*)d_in[11];
  const float* W3  = (const float*)d_in[12];
  const float* b3  = (const float*)d_in[13];
  const float* We1 = (const float*)d_in[14];
  const float* be1 = (const float*)d_in[15];
  const float* We2 = (const float*)d_in[16];
  const float* be2 = (const float*)d_in[17];
  const float* We3 = (const float*)d_in[18];
  const float* be3 = (const float*)d_in[19];

  float* wsf = (float*)d_ws;
  float* AGGE   = wsf + OFF_AGGE;
  float* AGGO   = wsf + OFF_AGGO;
  float* NMASK  = wsf + OFF_NMASK;
  float* POOLF  = wsf + OFF_POOLF;
  float* POOLS  = wsf + OFF_POOLS;
  float* CNT    = wsf + OFF_CNT;
  unsigned* LCOUNT = (unsigned*)(wsf + OFF_LCOUNT);
  unsigned long long* SEGKEY = (unsigned long long*)(wsf + OFF_SEGKEY);
  float* Hbuf   = wsf + OFF_H;
  float* NRA    = wsf + OFF_NRA;
  float* BIAS1  = wsf + OFF_BIAS1;
  int*   ELIST  = (int*)(wsf + OFF_ELIST);
  float* out = (float*)d_out;

  hipMemsetAsync(d_ws, 0, (size_t)ZERO_END * sizeof(float), stream);

  k_h     <<<NN/64,        256, 0, stream>>>(x, Wm1, Hbuf);
  k_edges <<<(EE*16)/256,  256, 0, stream>>>(ei, Hbuf, AGGE, AGGO, NMASK);
  k_node  <<<NN/8,         256, 0, stream>>>(Hbuf, AGGE, AGGO, Wm2, NMASK, NRA, POOLF, POOLS, CNT);
  k_graph <<<BB,           128, 0, stream>>>(POOLF, POOLS, CNT, Wg, y, We1, be1, BIAS1);
  k_bucket<<<EA/256,       256, 0, stream>>>(ei, y, LCOUNT, ELIST);
  k_mlp   <<<4*TPL,        256, 0, stream>>>(NRA, ei, W1, b1, W2, b2, W3, b3,
                                             We1, We2, be2, We3, be3,
                                             BIAS1, ELIST, LCOUNT, out, SEGKEY);
  k_final <<<1,             64, 0, stream>>>(SEGKEY, out);
}

// Round 3
// 1323.036 us; speedup vs baseline: 1.3013x; 1.3013x over previous
//
#include <hip/hip_runtime.h>

#define NN 25600
#define EE 409600
#define BB 64
#define NGR 400
#define DD 128
#define HH 64
#define RR 32
#define EA 204800              // available (odd) edges
#define TPL (EA/32)            // tiles per label bucket = 6400

// workspace layout (float offsets)
#define OFF_AGGE   0
#define OFF_AGGO   1638400
#define OFF_NMASK  3276800
#define OFF_POOLF  3302400
#define OFF_POOLS  3304448
#define OFF_CNT    3306496
#define OFF_LCOUNT 3306560     // 4 uints
#define OFF_SEGKEY 3306568     // 64 u64
#define ZERO_END   3306752
#define OFF_H      3306752
#define OFF_NRA    4945152
#define OFF_BIAS1  5764352
#define OFF_ELIST  5772544     // 4*EA ints
// weight packs overlay AGGE (dead after k_node); written by k_pack after k_node

typedef short bf16x8 __attribute__((ext_vector_type(8)));
typedef float floatx4 __attribute__((ext_vector_type(4)));
#define MFMA16 __builtin_amdgcn_mfma_f32_16x16x32_bf16

__device__ __forceinline__ float eluf(float v){ return v > 0.f ? v : expm1f(v); }

__device__ __forceinline__ void splitbf(float v, unsigned short& h, unsigned short& l){
  const unsigned u = __float_as_uint(v);
  h = (unsigned short)(u >> 16);
  const float hf = __uint_as_float(u & 0xFFFF0000u);
  l = (unsigned short)(__float_as_uint(v - hf) >> 16);
}
__device__ __forceinline__ float bf2f(unsigned short s){
  return __uint_as_float(((unsigned)s) << 16);
}

__device__ __forceinline__ unsigned long long packkey(float f, unsigned idx){
  unsigned u = __float_as_uint(f);
  u = (u & 0x80000000u) ? ~u : (u | 0x80000000u);
  return ((unsigned long long)u << 32) | (unsigned long long)(0xFFFFFFFFu - idx);
}

// ---------------- h = elu(x @ Wm1) ----------------
__global__ __launch_bounds__(256) void k_h(const float* __restrict__ x,
                                           const float* __restrict__ Wm1,
                                           float* __restrict__ h)
{
  __shared__ float xs[64][129];
  const int tid = threadIdx.x;
  const int n0 = blockIdx.x * 64;
  for (int idx = tid; idx < 64*128; idx += 256){
    int r = idx >> 7, c = idx & 127;
    xs[r][c] = x[(n0 + r)*DD + c];
  }
  __syncthreads();
  const int m = tid & 63, ng = tid >> 6;
  float4 acc[4];
  #pragma unroll
  for (int c = 0; c < 4; ++c) acc[c] = make_float4(0.f,0.f,0.f,0.f);
  for (int k = 0; k < 128; ++k){
    const float a = xs[m][k];
    const float* wr = Wm1 + k*64 + ng*16;
    #pragma unroll
    for (int c = 0; c < 4; ++c){
      const float4 w = *(const float4*)(wr + 4*c);
      acc[c].x += a*w.x; acc[c].y += a*w.y; acc[c].z += a*w.z; acc[c].w += a*w.w;
    }
  }
  float* hp = h + (n0 + m)*HH + ng*16;
  #pragma unroll
  for (int c = 0; c < 4; ++c){
    hp[4*c+0] = eluf(acc[c].x); hp[4*c+1] = eluf(acc[c].y);
    hp[4*c+2] = eluf(acc[c].z); hp[4*c+3] = eluf(acc[c].w);
  }
}

// ---------------- edge aggregation (parity split) + nmask ----------------
__global__ __launch_bounds__(256) void k_edges(const int* __restrict__ ei,
                                               const float* __restrict__ h,
                                               float* __restrict__ aggE,
                                               float* __restrict__ aggO,
                                               float* __restrict__ nmask)
{
  const int gidx = blockIdx.x*256 + threadIdx.x;
  const int e = gidx >> 4, c = gidx & 15;
  const int s = ei[e], d = ei[EE + e];
  const float4 v = *(const float4*)(h + s*HH + c*4);
  float* agg = (e & 1) ? aggO : aggE;
  float* ap = agg + d*HH + c*4;
  atomicAdd(ap+0, v.x); atomicAdd(ap+1, v.y);
  atomicAdd(ap+2, v.z); atomicAdd(ap+3, v.w);
  if (((e & 1) == 0) && (c == 0)){ nmask[s] = 1.0f; nmask[d] = 1.0f; }
}

// ---------------- node reps + pooled sums ----------------
__global__ __launch_bounds__(256) void k_node(const float* __restrict__ h,
                                              const float* __restrict__ aggE,
                                              const float* __restrict__ aggO,
                                              const float* __restrict__ Wm2,
                                              const float* __restrict__ nmask,
                                              float* __restrict__ nra,
                                              float* __restrict__ poolF,
                                              float* __restrict__ poolS,
                                              float* __restrict__ cntArr)
{
  __shared__ float hs[8][64], ae[8][64], ao[8][64];
  __shared__ float wm[64][32];
  const int tid = threadIdx.x;
  const int n0 = blockIdx.x * 8;
  for (int idx = tid; idx < 512; idx += 256){
    int i = idx >> 6, k = idx & 63, n = n0 + i;
    hs[i][k] = h[n*HH + k];
    ae[i][k] = aggE[n*HH + k];
    ao[i][k] = aggO[n*HH + k];
  }
  for (int idx = tid; idx < 2048; idx += 256) wm[idx >> 5][idx & 31] = Wm2[idx];
  __syncthreads();
  const int i = tid >> 5, r = tid & 31;
  const int n = n0 + i;
  float aF = 0.f, aS = 0.f, aA = 0.f;
  #pragma unroll 4
  for (int k = 0; k < 64; ++k){
    const float th = hs[i][k], te = ae[i][k], to = ao[i][k], w = wm[k][r];
    aF += (th + te + to) * w;
    aS += (th + te) * w;
    aA += (th + to) * w;
  }
  aF = eluf(aF); aS = eluf(aS); aA = eluf(aA);
  nra[n*RR + r] = aA;
  const int g = n / NGR;
  atomicAdd(&poolF[g*RR + r], aF);
  const float msk = nmask[n];
  if (msk != 0.f){
    atomicAdd(&poolS[g*RR + r], aS);
    if (r == 0) atomicAdd(&cntArr[g], 1.0f);
  }
}

// ---------------- pack all MLP weights into MFMA B-fragment hi/lo bf16 ----------------
// global tile ids: W1 [0,32) KT=2 N=256 | W2 [32,96) KT=8 N=128 | W3 [96,112) KT=4 N=64
//                  We1 [112,176) per-label 16 (KT=2 N=128) | We2 [176,240) per-label 16 (KT=4 N=64)
// tile t stored at pk + t*1024 shorts: [hi 64 lanes x 8][lo 64 lanes x 8]
__global__ __launch_bounds__(256) void k_pack(const float* __restrict__ W1,
                                              const float* __restrict__ W2,
                                              const float* __restrict__ W3,
                                              const float* __restrict__ We1,
                                              const float* __restrict__ We2,
                                              unsigned short* __restrict__ pk)
{
  const int t = blockIdx.x*4 + (threadIdx.x >> 6);   // 0..239
  const int L = threadIdx.x & 63;
  int tl, KT, N; const float* W;
  if (t < 32)      { tl = t;      KT = 2; N = 256; W = W1; }
  else if (t < 96) { tl = t-32;   KT = 8; N = 128; W = W2; }
  else if (t < 112){ tl = t-96;   KT = 4; N = 64;  W = W3; }
  else if (t < 176){ int u = t-112; int lb = u >> 4; tl = u & 15; KT = 2; N = 128; W = We1 + lb*16384; }
  else             { int u = t-176; int lb = u >> 4; tl = u & 15; KT = 4; N = 64;  W = We2 + lb*8192; }
  const int nt = tl / KT, kt = tl % KT;
  const int krow = kt*32 + (L >> 4)*8;
  const int col  = nt*16 + (L & 15);
  unsigned short* dh = pk + (unsigned)t*1024 + L*8;
  unsigned short* dl = dh + 512;
  #pragma unroll
  for (int j = 0; j < 8; ++j){
    const float v = W[(krow + j)*N + col];
    unsigned short h, l2;
    splitbf(v, h, l2);
    dh[j] = h; dl[j] = l2;
  }
}

// ---------------- per-graph diff and explainer bias ----------------
__global__ __launch_bounds__(128) void k_graph(const float* __restrict__ poolF,
                                               const float* __restrict__ poolS,
                                               const float* __restrict__ cnt,
                                               const float* __restrict__ Wg,
                                               const int* __restrict__ y,
                                               const float* __restrict__ We1,
                                               const float* __restrict__ be1,
                                               float* __restrict__ bias1)
{
  __shared__ float pd[32];
  __shared__ float dg[64];
  const int g = blockIdx.x, tid = threadIdx.x;
  if (tid < 32){
    const float c = cnt[g];
    const float pf = poolF[g*RR + tid] * (1.0f/400.0f);
    const float ps = poolS[g*RR + tid] / fmaxf(c, 1.0f);
    pd[tid] = pf - ps;
  }
  __syncthreads();
  if (tid < 64){
    float a = 0.f;
    #pragma unroll
    for (int r = 0; r < 32; ++r) a += pd[r] * Wg[r*64 + tid];
    dg[tid] = a;
  }
  __syncthreads();
  const int l = y[g];
  float acc = be1[l*128 + tid];
  #pragma unroll 8
  for (int j = 0; j < 64; ++j) acc += dg[j] * We1[l*16384 + (64 + j)*128 + tid];
  bias1[g*128 + tid] = acc;
}

// ---------------- bucket available edges by graph label ----------------
__global__ __launch_bounds__(256) void k_bucket(const int* __restrict__ ei,
                                                const int* __restrict__ y,
                                                unsigned* __restrict__ lcount,
                                                int* __restrict__ elist)
{
  const int i = blockIdx.x*256 + threadIdx.x;
  const int e = 2*i + 1;
  const int s = ei[e];
  const int l = y[s / NGR];
  const int lane = threadIdx.x & 63;
  #pragma unroll
  for (int lb = 0; lb < 4; ++lb){
    const unsigned long long msk = __ballot(l == lb);
    if (l == lb){
      const int leader = __builtin_ctzll(msk);
      const unsigned cnt = (unsigned)__popcll(msk);
      unsigned base = 0;
      if (lane == leader) base = atomicAdd(&lcount[lb], cnt);
      base = (unsigned)__shfl((int)base, leader);
      const unsigned rank = (unsigned)__popcll(msk & ((1ull << lane) - 1ull));
      elist[lb*EA + (int)(base + rank)] = i;
    }
  }
}

// ---------------- MFMA split-bf16 layer ----------------
// wave `mt` computes rows [mt*16, mt*16+16) for all N columns.
template<int K, int N, int SIN, int SOUT, bool DOELU, bool ROWBIAS>
__device__ __forceinline__ void layerM(const unsigned short (*__restrict__ Ih)[SIN],
                                       const unsigned short (*__restrict__ Il)[SIN],
                                       unsigned short (*__restrict__ Oh)[SOUT],
                                       unsigned short (*__restrict__ Ol)[SOUT],
                                       const unsigned short* __restrict__ pk,
                                       const float* __restrict__ bias,
                                       const int* __restrict__ gA,
                                       int mt, int lane)
{
  constexpr int KT = K/32, NT = N/16;
  const int c = lane & 15, q = lane >> 4;
  floatx4 acc[NT];
  #pragma unroll
  for (int nt = 0; nt < NT; ++nt){
    if (ROWBIAS){
      #pragma unroll
      for (int r = 0; r < 4; ++r)
        acc[nt][r] = bias[gA[mt*16 + q*4 + r]*128 + nt*16 + c];
    } else {
      const float bv = bias[nt*16 + c];
      floatx4 a; a[0] = bv; a[1] = bv; a[2] = bv; a[3] = bv;
      acc[nt] = a;
    }
  }
  const unsigned short* ahp = &Ih[mt*16 + c][q*8];
  const unsigned short* alp = &Il[mt*16 + c][q*8];
  #pragma unroll
  for (int kt = 0; kt < KT; ++kt){
    const bf16x8 ah = *(const bf16x8*)(ahp + kt*32);
    const bf16x8 al = *(const bf16x8*)(alp + kt*32);
    #pragma unroll
    for (int nt = 0; nt < NT; ++nt){
      const unsigned short* bp = pk + (unsigned)((nt*KT + kt)*1024) + lane*8;
      const bf16x8 bh = *(const bf16x8*)bp;
      const bf16x8 bl = *(const bf16x8*)(bp + 512);
      acc[nt] = MFMA16(ah, bh, acc[nt], 0, 0, 0);
      acc[nt] = MFMA16(al, bh, acc[nt], 0, 0, 0);
      acc[nt] = MFMA16(ah, bl, acc[nt], 0, 0, 0);
    }
  }
  #pragma unroll
  for (int nt = 0; nt < NT; ++nt){
    #pragma unroll
    for (int r = 0; r < 4; ++r){
      float v = acc[nt][r];
      if (DOELU) v = eluf(v);
      unsigned short h, l2;
      splitbf(v, h, l2);
      const int row = mt*16 + q*4 + r, col = nt*16 + c;
      Oh[row][col] = h; Ol[row][col] = l2;
    }
  }
}

// ---------------- fused per-edge MLP (MFMA) ----------------
__global__ __launch_bounds__(128) void k_mlp(const float* __restrict__ nra,
                                             const int* __restrict__ ei,
                                             const unsigned short* __restrict__ pk,
                                             const float* __restrict__ b1,
                                             const float* __restrict__ b2,
                                             const float* __restrict__ b3,
                                             const float* __restrict__ be2,
                                             const float* __restrict__ We3,
                                             const float* __restrict__ be3,
                                             const float* __restrict__ bias1,
                                             const int* __restrict__ elist,
                                             const unsigned* __restrict__ lcount,
                                             float* __restrict__ probs,
                                             unsigned long long* __restrict__ segkey)
{
  __shared__ unsigned short Xh[32][264], Xl[32][264];
  __shared__ unsigned short Yh[32][136], Yl[32][136];
  __shared__ int iA[32], sA[32], dA[32], gA[32];
  const int l = blockIdx.x / TPL;
  const int t = blockIdx.x % TPL;
  const unsigned cnt = lcount[l];
  const int base = t * 32;
  if ((unsigned)base >= cnt) return;
  const int valid = min(32, (int)(cnt - (unsigned)base));
  const int tid = threadIdx.x;
  const int wv = tid >> 6, lane = tid & 63;
  if (tid < 32){
    const int mm = (tid < valid) ? tid : 0;
    const int i = elist[l*EA + base + mm];
    const int e = 2*i + 1;
    const int s = ei[e], d = ei[EE + e];
    iA[tid] = i; sA[tid] = s; dA[tid] = d; gA[tid] = s / NGR;
  }
  __syncthreads();
  { // gather in0 = [nr_ava[src] | nr_ava[dst]] split into Yh/Yl cols 0..63
    const int m = tid >> 2, t4 = tid & 3;
    const int node = (t4 < 2) ? sA[m] : dA[m];
    const int off = (t4 & 1) * 16;
    const float* np_ = nra + node*RR + off;
    const int cb = ((t4 < 2) ? 0 : 32) + off;
    #pragma unroll
    for (int jj = 0; jj < 16; ++jj){
      unsigned short h, l2;
      splitbf(np_[jj], h, l2);
      Yh[m][cb + jj] = h; Yl[m][cb + jj] = l2;
    }
  }
  __syncthreads();
  layerM< 64,256,136,264,true ,false>(Yh,Yl,Xh,Xl, pk,                           b1,          gA, wv, lane);
  __syncthreads();
  layerM<256,128,264,136,true ,false>(Xh,Xl,Yh,Yl, pk + 32*1024,                 b2,          gA, wv, lane);
  __syncthreads();
  layerM<128, 64,136,264,false,false>(Yh,Yl,Xh,Xl, pk + 96*1024,                 b3,          gA, wv, lane);
  __syncthreads();
  layerM< 64,128,264,136,true ,true >(Xh,Xl,Yh,Yl, pk + (112 + l*16)*1024,       bias1,       gA, wv, lane);
  __syncthreads();
  layerM<128, 64,136,264,true ,false>(Yh,Yl,Xh,Xl, pk + (176 + l*16)*1024,       be2 + l*64,  gA, wv, lane);
  __syncthreads();
  { // score = X5 . We3[l] + be3[l]; 4 threads per edge
    const int m = tid >> 2, part = tid & 3;
    const float* w3p = We3 + l*64 + part*16;
    const unsigned short* xh = &Xh[m][part*16];
    const unsigned short* xl = &Xl[m][part*16];
    float s = 0.f;
    #pragma unroll
    for (int kk = 0; kk < 16; ++kk)
      s += (bf2f(xh[kk]) + bf2f(xl[kk])) * w3p[kk];
    s += __shfl_down(s, 2);
    s += __shfl_down(s, 1);
    if (part == 0 && m < valid){
      s += be3[l];
      const int i = iA[m];
      probs[i] = s;
      atomicMax(&segkey[gA[m]], packkey(s, (unsigned)i));
    }
  }
}

// ---------------- finalize outputs ----------------
__global__ void k_final(const unsigned long long* __restrict__ segkey, float* __restrict__ out)
{
  const int g = threadIdx.x;
  if (g < BB){
    const unsigned long long key = segkey[g];
    const unsigned u = (unsigned)(key >> 32);
    const float mx = (u & 0x80000000u) ? __uint_as_float(u & 0x7FFFFFFFu)
                                       : __uint_as_float(~u);
    const unsigned idx = 0xFFFFFFFFu - (unsigned)(key & 0xFFFFFFFFull);
    out[EA + g]        = mx;
    out[EA + BB + g]   = (float)idx;
    out[EA + 2*BB + g] = (float)g;
  }
}

extern "C" void kernel_launch(void* const* d_in, const int* in_sizes, int n_in,
                              void* d_out, int out_size, void* d_ws, size_t ws_size,
                              hipStream_t stream)
{
  (void)in_sizes; (void)n_in; (void)out_size; (void)ws_size;
  const float* x   = (const float*)d_in[0];
  const int*   ei  = (const int*)  d_in[1];
  const int*   y   = (const int*)  d_in[3];
  const float* Wm1 = (const float*)d_in[5];
  const float* Wm2 = (const float*)d_in[6];
  const float* Wg  = (const float*)d_in[7];
  const float* W1  = (const float*)d_in[8];
  const float* b1  = (const float*)d_in[9];
  const float* W2  = (const float*)d_in[10];
  const float* b2  = (const float*)d_in[11];
  const float* W3  = (const float*)d_in[12];
  const float* b3  = (const float*)d_in[13];
  const float* We1 = (const float*)d_in[14];
  const float* be1 = (const float*)d_in[15];
  const float* We2 = (const float*)d_in[16];
  const float* be2 = (const float*)d_in[17];
  const float* We3 = (const float*)d_in[18];
  const float* be3 = (const float*)d_in[19];

  float* wsf = (float*)d_ws;
  float* AGGE   = wsf + OFF_AGGE;
  float* AGGO   = wsf + OFF_AGGO;
  float* NMASK  = wsf + OFF_NMASK;
  float* POOLF  = wsf + OFF_POOLF;
  float* POOLS  = wsf + OFF_POOLS;
  float* CNT    = wsf + OFF_CNT;
  unsigned* LCOUNT = (unsigned*)(wsf + OFF_LCOUNT);
  unsigned long long* SEGKEY = (unsigned long long*)(wsf + OFF_SEGKEY);
  float* Hbuf   = wsf + OFF_H;
  float* NRA    = wsf + OFF_NRA;
  float* BIAS1  = wsf + OFF_BIAS1;
  int*   ELIST  = (int*)(wsf + OFF_ELIST);
  unsigned short* PK = (unsigned short*)(wsf + OFF_AGGE);  // overlays AGGE, written after k_node
  float* out = (float*)d_out;

  hipMemsetAsync(d_ws, 0, (size_t)ZERO_END * sizeof(float), stream);

  k_h     <<<NN/64,        256, 0, stream>>>(x, Wm1, Hbuf);
  k_edges <<<(EE*16)/256,  256, 0, stream>>>(ei, Hbuf, AGGE, AGGO, NMASK);
  k_node  <<<NN/8,         256, 0, stream>>>(Hbuf, AGGE, AGGO, Wm2, NMASK, NRA, POOLF, POOLS, CNT);
  k_pack  <<<60,           256, 0, stream>>>(W1, W2, W3, We1, We2, PK);
  k_graph <<<BB,           128, 0, stream>>>(POOLF, POOLS, CNT, Wg, y, We1, be1, BIAS1);
  k_bucket<<<EA/256,       256, 0, stream>>>(ei, y, LCOUNT, ELIST);
  k_mlp   <<<4*TPL,        128, 0, stream>>>(NRA, ei, PK, b1, b2, b3, be2, We3, be3,
                                             BIAS1, ELIST, LCOUNT, out, SEGKEY);
  k_final <<<1,             64, 0, stream>>>(SEGKEY, out);
}

// Round 4
// 1232.962 us; speedup vs baseline: 1.3963x; 1.0731x over previous
//
#include <hip/hip_runtime.h>

#define NN 25600
#define EE 409600
#define BB 64
#define NGR 400
#define DD 128
#define HH 64
#define RR 32
#define EA 204800              // available (odd) edges
#define TPL (EA/32)            // tiles per label bucket = 6400

// workspace layout (float offsets)
#define OFF_AGGE   0
#define OFF_AGGO   1638400
#define OFF_NMASK  3276800
#define OFF_POOLF  3302400
#define OFF_POOLS  3304448
#define OFF_CNT    3306496
#define OFF_LCOUNT 3306560     // 4 uints
#define OFF_SEGKEY 3306568     // 64 u64
#define ZERO_END   3306752
#define OFF_H      3306752
#define OFF_NRA    4945152
#define OFF_BIAS1  5764352
#define OFF_ELIST  5772544     // 4*EA ints
// weight packs overlay AGGE (dead after k_node); written by k_pack after k_node

typedef short bf16x8 __attribute__((ext_vector_type(8)));
typedef float floatx4 __attribute__((ext_vector_type(4)));
#define MFMA16 __builtin_amdgcn_mfma_f32_16x16x32_bf16

__device__ __forceinline__ float eluf(float v){ return v > 0.f ? v : expm1f(v); }

__device__ __forceinline__ void splitbf(float v, unsigned short& h, unsigned short& l){
  const unsigned u = __float_as_uint(v);
  h = (unsigned short)(u >> 16);
  const float hf = __uint_as_float(u & 0xFFFF0000u);
  l = (unsigned short)(__float_as_uint(v - hf) >> 16);
}
__device__ __forceinline__ float bf2f(unsigned short s){
  return __uint_as_float(((unsigned)s) << 16);
}

__device__ __forceinline__ unsigned long long packkey(float f, unsigned idx){
  unsigned u = __float_as_uint(f);
  u = (u & 0x80000000u) ? ~u : (u | 0x80000000u);
  return ((unsigned long long)u << 32) | (unsigned long long)(0xFFFFFFFFu - idx);
}

// ---------------- h = elu(x @ Wm1) ----------------
__global__ __launch_bounds__(256) void k_h(const float* __restrict__ x,
                                           const float* __restrict__ Wm1,
                                           float* __restrict__ h)
{
  __shared__ float xs[64][129];
  const int tid = threadIdx.x;
  const int n0 = blockIdx.x * 64;
  for (int idx = tid; idx < 64*128; idx += 256){
    int r = idx >> 7, c = idx & 127;
    xs[r][c] = x[(n0 + r)*DD + c];
  }
  __syncthreads();
  const int m = tid & 63, ng = tid >> 6;
  float4 acc[4];
  #pragma unroll
  for (int c = 0; c < 4; ++c) acc[c] = make_float4(0.f,0.f,0.f,0.f);
  for (int k = 0; k < 128; ++k){
    const float a = xs[m][k];
    const float* wr = Wm1 + k*64 + ng*16;
    #pragma unroll
    for (int c = 0; c < 4; ++c){
      const float4 w = *(const float4*)(wr + 4*c);
      acc[c].x += a*w.x; acc[c].y += a*w.y; acc[c].z += a*w.z; acc[c].w += a*w.w;
    }
  }
  float* hp = h + (n0 + m)*HH + ng*16;
  #pragma unroll
  for (int c = 0; c < 4; ++c){
    hp[4*c+0] = eluf(acc[c].x); hp[4*c+1] = eluf(acc[c].y);
    hp[4*c+2] = eluf(acc[c].z); hp[4*c+3] = eluf(acc[c].w);
  }
}

// ---------------- edge aggregation via LDS (no global atomics) ----------------
// block = (graph g, parity p, col-half ch). LDS 400x32 accumulator + edge queue.
__global__ __launch_bounds__(256) void k_edges(const int* __restrict__ ei,
                                               const float* __restrict__ h,
                                               float* __restrict__ aggE,
                                               float* __restrict__ aggO,
                                               float* __restrict__ nmask)
{
  __shared__ float acc[400*32];
  __shared__ int q[2048];
  __shared__ int qn;
  __shared__ unsigned char mk[400];
  const int b = blockIdx.x;
  const int g = b >> 2, p = (b >> 1) & 1, ch = b & 1;
  const int tid = threadIdx.x;
  const int lane = tid & 63;
  const int nlo = g * NGR;

  for (int i = tid; i < 400*32/4; i += 256) ((float4*)acc)[i] = make_float4(0.f,0.f,0.f,0.f);
  if (tid < 400) mk[tid] = 0;
  if (tid == 0) qn = 0;
  __syncthreads();

  for (int w0 = 0; w0 < EE/2; w0 += 20480){
    // scan parity-p edges, compact matches into queue
    for (int ii = w0 + tid; ii < w0 + 20480; ii += 256){
      const int e = 2*ii + p;
      const int d = ei[EE + e];
      const bool m = ((unsigned)(d - nlo) < (unsigned)NGR);
      const unsigned long long msk = __ballot(m);
      if (m){
        const int leader = __builtin_ctzll(msk);
        int basepos = 0;
        if (lane == leader) basepos = atomicAdd(&qn, __popcll(msk));
        basepos = __shfl(basepos, leader);
        const int rank = (int)__popcll(msk & ((1ull << lane) - 1ull));
        if (basepos + rank < 2048) q[basepos + rank] = e;
      }
    }
    __syncthreads();
    const int nq = (qn < 2048) ? qn : 2048;
    // drain: 8 lanes per edge, accumulate 32 cols into LDS
    for (int j = (tid >> 3); j < nq; j += 32){
      const int e = q[j];
      const int s = ei[e];
      const int d = ei[EE + e] - nlo;
      const int c8 = tid & 7;
      const float4 v = *(const float4*)(h + s*HH + ch*32 + c8*4);
      const float* vp = (const float*)&v;
      #pragma unroll
      for (int i3 = 0; i3 < 4; ++i3){
        const int col = (c8*4 + i3 + d) & 31;   // rotate to spread banks
        atomicAdd(&acc[d*32 + col], vp[i3]);
      }
      if (p == 0 && ch == 0 && c8 == 0){ mk[s - nlo] = 1; mk[d] = 1; }
    }
    __syncthreads();
    if (tid == 0) qn = 0;
    __syncthreads();
  }

  float* agg = p ? aggO : aggE;
  for (int idx = tid; idx < 400*32; idx += 256){
    const int d = idx >> 5, col = idx & 31;
    agg[(nlo + d)*HH + ch*32 + col] = acc[d*32 + ((col + d) & 31)];
  }
  if (p == 0 && ch == 0){
    for (int idx = tid; idx < 400; idx += 256) nmask[nlo + idx] = (float)mk[idx];
  }
}

// ---------------- node reps + pooled sums ----------------
__global__ __launch_bounds__(256) void k_node(const float* __restrict__ h,
                                              const float* __restrict__ aggE,
                                              const float* __restrict__ aggO,
                                              const float* __restrict__ Wm2,
                                              const float* __restrict__ nmask,
                                              float* __restrict__ nra,
                                              float* __restrict__ poolF,
                                              float* __restrict__ poolS,
                                              float* __restrict__ cntArr)
{
  __shared__ float hs[8][64], ae[8][64], ao[8][64];
  __shared__ float wm[64][32];
  const int tid = threadIdx.x;
  const int n0 = blockIdx.x * 8;
  for (int idx = tid; idx < 512; idx += 256){
    int i = idx >> 6, k = idx & 63, n = n0 + i;
    hs[i][k] = h[n*HH + k];
    ae[i][k] = aggE[n*HH + k];
    ao[i][k] = aggO[n*HH + k];
  }
  for (int idx = tid; idx < 2048; idx += 256) wm[idx >> 5][idx & 31] = Wm2[idx];
  __syncthreads();
  const int i = tid >> 5, r = tid & 31;
  const int n = n0 + i;
  float aF = 0.f, aS = 0.f, aA = 0.f;
  #pragma unroll 4
  for (int k = 0; k < 64; ++k){
    const float th = hs[i][k], te = ae[i][k], to = ao[i][k], w = wm[k][r];
    aF += (th + te + to) * w;
    aS += (th + te) * w;
    aA += (th + to) * w;
  }
  aF = eluf(aF); aS = eluf(aS); aA = eluf(aA);
  nra[n*RR + r] = aA;
  const int g = n / NGR;
  atomicAdd(&poolF[g*RR + r], aF);
  const float msk = nmask[n];
  if (msk != 0.f){
    atomicAdd(&poolS[g*RR + r], aS);
    if (r == 0) atomicAdd(&cntArr[g], 1.0f);
  }
}

// ---------------- pack all MLP weights into MFMA B-fragment hi/lo bf16 ----------------
__global__ __launch_bounds__(256) void k_pack(const float* __restrict__ W1,
                                              const float* __restrict__ W2,
                                              const float* __restrict__ W3,
                                              const float* __restrict__ We1,
                                              const float* __restrict__ We2,
                                              unsigned short* __restrict__ pk)
{
  const int t = blockIdx.x*4 + (threadIdx.x >> 6);   // 0..239
  const int L = threadIdx.x & 63;
  int tl, KT, N; const float* W;
  if (t < 32)      { tl = t;      KT = 2; N = 256; W = W1; }
  else if (t < 96) { tl = t-32;   KT = 8; N = 128; W = W2; }
  else if (t < 112){ tl = t-96;   KT = 4; N = 64;  W = W3; }
  else if (t < 176){ int u = t-112; int lb = u >> 4; tl = u & 15; KT = 2; N = 128; W = We1 + lb*16384; }
  else             { int u = t-176; int lb = u >> 4; tl = u & 15; KT = 4; N = 64;  W = We2 + lb*8192; }
  const int nt = tl / KT, kt = tl % KT;
  const int krow = kt*32 + (L >> 4)*8;
  const int col  = nt*16 + (L & 15);
  unsigned short* dh = pk + (unsigned)t*1024 + L*8;
  unsigned short* dl = dh + 512;
  #pragma unroll
  for (int j = 0; j < 8; ++j){
    const float v = W[(krow + j)*N + col];
    unsigned short h, l2;
    splitbf(v, h, l2);
    dh[j] = h; dl[j] = l2;
  }
}

// ---------------- per-graph diff and explainer bias ----------------
__global__ __launch_bounds__(128) void k_graph(const float* __restrict__ poolF,
                                               const float* __restrict__ poolS,
                                               const float* __restrict__ cnt,
                                               const float* __restrict__ Wg,
                                               const int* __restrict__ y,
                                               const float* __restrict__ We1,
                                               const float* __restrict__ be1,
                                               float* __restrict__ bias1)
{
  __shared__ float pd[32];
  __shared__ float dg[64];
  const int g = blockIdx.x, tid = threadIdx.x;
  if (tid < 32){
    const float c = cnt[g];
    const float pf = poolF[g*RR + tid] * (1.0f/400.0f);
    const float ps = poolS[g*RR + tid] / fmaxf(c, 1.0f);
    pd[tid] = pf - ps;
  }
  __syncthreads();
  if (tid < 64){
    float a = 0.f;
    #pragma unroll
    for (int r = 0; r < 32; ++r) a += pd[r] * Wg[r*64 + tid];
    dg[tid] = a;
  }
  __syncthreads();
  const int l = y[g];
  float acc = be1[l*128 + tid];
  #pragma unroll 8
  for (int j = 0; j < 64; ++j) acc += dg[j] * We1[l*16384 + (64 + j)*128 + tid];
  bias1[g*128 + tid] = acc;
}

// ---------------- bucket available edges by graph label ----------------
__global__ __launch_bounds__(256) void k_bucket(const int* __restrict__ ei,
                                                const int* __restrict__ y,
                                                unsigned* __restrict__ lcount,
                                                int* __restrict__ elist)
{
  const int i = blockIdx.x*256 + threadIdx.x;
  const int e = 2*i + 1;
  const int s = ei[e];
  const int l = y[s / NGR];
  const int lane = threadIdx.x & 63;
  #pragma unroll
  for (int lb = 0; lb < 4; ++lb){
    const unsigned long long msk = __ballot(l == lb);
    if (l == lb){
      const int leader = __builtin_ctzll(msk);
      const unsigned cnt = (unsigned)__popcll(msk);
      unsigned base = 0;
      if (lane == leader) base = atomicAdd(&lcount[lb], cnt);
      base = (unsigned)__shfl((int)base, leader);
      const unsigned rank = (unsigned)__popcll(msk & ((1ull << lane) - 1ull));
      elist[lb*EA + (int)(base + rank)] = i;
    }
  }
}

// ---------------- MFMA split-bf16 layer: 4 waves split N, each wave 2 m-tiles ----------------
template<int K, int N, bool DOELU, int SIN, int SOUT, bool ROWBIAS>
__device__ __forceinline__ void layerM(const unsigned short (*__restrict__ Ih)[SIN],
                                       const unsigned short (*__restrict__ Il)[SIN],
                                       unsigned short (*__restrict__ Oh)[SOUT],
                                       unsigned short (*__restrict__ Ol)[SOUT],
                                       const unsigned short* __restrict__ pk,
                                       const float* __restrict__ bias,
                                       const int* __restrict__ gA,
                                       int wv, int lane)
{
  constexpr int KT = K/32, NTW = N/64;   // k-tiles; n-tiles per wave
  const int c = lane & 15, q = lane >> 4;
  floatx4 acc[2][NTW];
  #pragma unroll
  for (int ms = 0; ms < 2; ++ms){
    #pragma unroll
    for (int nt = 0; nt < NTW; ++nt){
      const int col = (wv*NTW + nt)*16 + c;
      if (ROWBIAS){
        #pragma unroll
        for (int r = 0; r < 4; ++r)
          acc[ms][nt][r] = bias[gA[ms*16 + q*4 + r]*128 + col];
      } else {
        const float bv = bias[col];
        acc[ms][nt][0]=bv; acc[ms][nt][1]=bv; acc[ms][nt][2]=bv; acc[ms][nt][3]=bv;
      }
    }
  }
  #pragma unroll
  for (int kt = 0; kt < KT; ++kt){
    const bf16x8 ah0 = *(const bf16x8*)&Ih[c     ][kt*32 + q*8];
    const bf16x8 al0 = *(const bf16x8*)&Il[c     ][kt*32 + q*8];
    const bf16x8 ah1 = *(const bf16x8*)&Ih[16 + c][kt*32 + q*8];
    const bf16x8 al1 = *(const bf16x8*)&Il[16 + c][kt*32 + q*8];
    #pragma unroll
    for (int nt = 0; nt < NTW; ++nt){
      const unsigned short* bp = pk + (unsigned)(((wv*NTW + nt)*KT + kt)*1024) + lane*8;
      const bf16x8 bh = *(const bf16x8*)bp;
      const bf16x8 bl = *(const bf16x8*)(bp + 512);
      acc[0][nt] = MFMA16(ah0, bh, acc[0][nt], 0, 0, 0);
      acc[1][nt] = MFMA16(ah1, bh, acc[1][nt], 0, 0, 0);
      acc[0][nt] = MFMA16(al0, bh, acc[0][nt], 0, 0, 0);
      acc[1][nt] = MFMA16(al1, bh, acc[1][nt], 0, 0, 0);
      acc[0][nt] = MFMA16(ah0, bl, acc[0][nt], 0, 0, 0);
      acc[1][nt] = MFMA16(ah1, bl, acc[1][nt], 0, 0, 0);
    }
  }
  #pragma unroll
  for (int ms = 0; ms < 2; ++ms){
    #pragma unroll
    for (int nt = 0; nt < NTW; ++nt){
      const int col = (wv*NTW + nt)*16 + c;
      #pragma unroll
      for (int r = 0; r < 4; ++r){
        float v = acc[ms][nt][r];
        if (DOELU) v = eluf(v);
        unsigned short h, l2;
        splitbf(v, h, l2);
        const int row = ms*16 + q*4 + r;
        Oh[row][col] = h; Ol[row][col] = l2;
      }
    }
  }
}

// ---------------- fused per-edge MLP (MFMA) ----------------
__global__ __launch_bounds__(256) void k_mlp(const float* __restrict__ nra,
                                             const int* __restrict__ ei,
                                             const unsigned short* __restrict__ pk,
                                             const float* __restrict__ b1,
                                             const float* __restrict__ b2,
                                             const float* __restrict__ b3,
                                             const float* __restrict__ be2,
                                             const float* __restrict__ We3,
                                             const float* __restrict__ be3,
                                             const float* __restrict__ bias1,
                                             const int* __restrict__ elist,
                                             const unsigned* __restrict__ lcount,
                                             float* __restrict__ probs,
                                             unsigned long long* __restrict__ segkey)
{
  __shared__ unsigned short Xh[32][264], Xl[32][264];
  __shared__ unsigned short Yh[32][136], Yl[32][136];
  __shared__ int iA[32], sA[32], dA[32], gA[32];
  const int l = blockIdx.x / TPL;
  const int t = blockIdx.x % TPL;
  const unsigned cnt = lcount[l];
  const int base = t * 32;
  if ((unsigned)base >= cnt) return;
  const int valid = min(32, (int)(cnt - (unsigned)base));
  const int tid = threadIdx.x;
  const int wv = tid >> 6, lane = tid & 63;
  if (tid < 32){
    const int mm = (tid < valid) ? tid : 0;
    const int i = elist[l*EA + base + mm];
    const int e = 2*i + 1;
    const int s = ei[e], d = ei[EE + e];
    iA[tid] = i; sA[tid] = s; dA[tid] = d; gA[tid] = s / NGR;
  }
  __syncthreads();
  { // gather in0 = [nr_ava[src] | nr_ava[dst]] split into Yh/Yl cols 0..63
    const int m = tid >> 3, t8 = tid & 7;
    const int node = (t8 < 4) ? sA[m] : dA[m];
    const int off = (t8 & 3) * 8;
    const float* np_ = nra + node*RR + off;
    const int cb = ((t8 < 4) ? 0 : 32) + off;
    #pragma unroll
    for (int jj = 0; jj < 8; ++jj){
      unsigned short h, l2;
      splitbf(np_[jj], h, l2);
      Yh[m][cb + jj] = h; Yl[m][cb + jj] = l2;
    }
  }
  __syncthreads();
  layerM< 64,256,true ,136,264,false>(Yh,Yl,Xh,Xl, pk,                     b1,         gA, wv, lane);
  __syncthreads();
  layerM<256,128,true ,264,136,false>(Xh,Xl,Yh,Yl, pk + 32*1024,           b2,         gA, wv, lane);
  __syncthreads();
  layerM<128, 64,false,136,264,false>(Yh,Yl,Xh,Xl, pk + 96*1024,           b3,         gA, wv, lane);
  __syncthreads();
  layerM< 64,128,true ,264,136,true >(Xh,Xl,Yh,Yl, pk + (112 + l*16)*1024, bias1,      gA, wv, lane);
  __syncthreads();
  layerM<128, 64,true ,136,264,false>(Yh,Yl,Xh,Xl, pk + (176 + l*16)*1024, be2 + l*64, gA, wv, lane);
  __syncthreads();
  if (tid < 128){ // score = X5 . We3[l] + be3[l]; 4 threads per edge
    const int m = tid >> 2, part = tid & 3;
    const float* w3p = We3 + l*64 + part*16;
    const unsigned short* xh = &Xh[m][part*16];
    const unsigned short* xl = &Xl[m][part*16];
    float s = 0.f;
    #pragma unroll
    for (int kk = 0; kk < 16; ++kk)
      s += (bf2f(xh[kk]) + bf2f(xl[kk])) * w3p[kk];
    s += __shfl_down(s, 2);
    s += __shfl_down(s, 1);
    if (part == 0 && m < valid){
      s += be3[l];
      const int i = iA[m];
      probs[i] = s;
      atomicMax(&segkey[gA[m]], packkey(s, (unsigned)i));
    }
  }
}

// ---------------- finalize outputs ----------------
__global__ void k_final(const unsigned long long* __restrict__ segkey, float* __restrict__ out)
{
  const int g = threadIdx.x;
  if (g < BB){
    const unsigned long long key = segkey[g];
    const unsigned u = (unsigned)(key >> 32);
    const float mx = (u & 0x80000000u) ? __uint_as_float(u & 0x7FFFFFFFu)
                                       : __uint_as_float(~u);
    const unsigned idx = 0xFFFFFFFFu - (unsigned)(key & 0xFFFFFFFFull);
    out[EA + g]        = mx;
    out[EA + BB + g]   = (float)idx;
    out[EA + 2*BB + g] = (float)g;
  }
}

extern "C" void kernel_launch(void* const* d_in, const int* in_sizes, int n_in,
                              void* d_out, int out_size, void* d_ws, size_t ws_size,
                              hipStream_t stream)
{
  (void)in_sizes; (void)n_in; (void)out_size; (void)ws_size;
  const float* x   = (const float*)d_in[0];
  const int*   ei  = (const int*)  d_in[1];
  const int*   y   = (const int*)  d_in[3];
  const float* Wm1 = (const float*)d_in[5];
  const float* Wm2 = (const float*)d_in[6];
  const float* Wg  = (const float*)d_in[7];
  const float* W1  = (const float*)d_in[8];
  const float* b1  = (const float*)d_in[9];
  const float* W2  = (const float*)d_in[10];
  const float* b2  = (const float*)d_in[11];
  const float* W3  = (const float*)d_in[12];
  const float* b3  = (const float*)d_in[13];
  const float* We1 = (const float*)d_in[14];
  const float* be1 = (const float*)d_in[15];
  const float* We2 = (const float*)d_in[16];
  const float* be2 = (const float*)d_in[17];
  const float* We3 = (const float*)d_in[18];
  const float* be3 = (const float*)d_in[19];

  float* wsf = (float*)d_ws;
  float* AGGE   = wsf + OFF_AGGE;
  float* AGGO   = wsf + OFF_AGGO;
  float* NMASK  = wsf + OFF_NMASK;
  float* POOLF  = wsf + OFF_POOLF;
  float* POOLS  = wsf + OFF_POOLS;
  float* CNT    = wsf + OFF_CNT;
  unsigned* LCOUNT = (unsigned*)(wsf + OFF_LCOUNT);
  unsigned long long* SEGKEY = (unsigned long long*)(wsf + OFF_SEGKEY);
  float* Hbuf   = wsf + OFF_H;
  float* NRA    = wsf + OFF_NRA;
  float* BIAS1  = wsf + OFF_BIAS1;
  int*   ELIST  = (int*)(wsf + OFF_ELIST);
  unsigned short* PK = (unsigned short*)(wsf + OFF_AGGE);  // overlays AGGE, written after k_node
  float* out = (float*)d_out;

  // only pools/counters/keys need zeroing now (agg + nmask are fully written by k_edges)
  hipMemsetAsync(wsf + OFF_POOLF, 0, (size_t)(ZERO_END - OFF_POOLF) * sizeof(float), stream);

  k_h     <<<NN/64,   256, 0, stream>>>(x, Wm1, Hbuf);
  k_edges <<<BB*4,    256, 0, stream>>>(ei, Hbuf, AGGE, AGGO, NMASK);
  k_node  <<<NN/8,    256, 0, stream>>>(Hbuf, AGGE, AGGO, Wm2, NMASK, NRA, POOLF, POOLS, CNT);
  k_pack  <<<60,      256, 0, stream>>>(W1, W2, W3, We1, We2, PK);
  k_graph <<<BB,      128, 0, stream>>>(POOLF, POOLS, CNT, Wg, y, We1, be1, BIAS1);
  k_bucket<<<EA/256,  256, 0, stream>>>(ei, y, LCOUNT, ELIST);
  k_mlp   <<<4*TPL,   256, 0, stream>>>(NRA, ei, PK, b1, b2, b3, be2, We3, be3,
                                        BIAS1, ELIST, LCOUNT, out, SEGKEY);
  k_final <<<1,        64, 0, stream>>>(SEGKEY, out);
}